// Round 5
// baseline (52.369 us; speedup 1.0000x reference)
//
#include <hip/hip_runtime.h>

// IntervalTimeEncoder: out[b,l,e] = W[e, idx(b,l)] + bias[e]
// idx(b,l) = clamp(trunc((ts[b,l]-ts[b,l-1]) / 100000.0f * 100.0f), 0, 100), idx(b,0)=0
//
// Inputs (setup_inputs order):
//   d_in[0] = inputs    int64  [128,4096]   (UNUSED by reference)
//   d_in[1] = timestamp f32    [128,4096]
//   d_in[2] = W         f32    [128,101]
//   d_in[3] = b         f32    [128]
// Output: f32 [128,4096,128] = 256 MiB -> write-streaming bound.
// Floor: 268.4 MB / 7.08 TB/s (measured fill rate on this chip) = 37.9 us.
//
// Round 5: round-4 retry — __builtin_nontemporal_store needs a NATIVE vector
// type (clang ext_vector), not HIP's float4 class. Structure unchanged:
// single kernel, 4 hot fused table rows in LDS, 4 independent nt float4
// stores per group-iteration. Cold W-direct path keeps correctness for
// any idx > 3 (never taken with this data: gaps <= 3000).

#define NBINS  100
#define EMB    128
#define LLEN   4096
#define NROWS  (128 * LLEN)            // 524288

typedef float vf4 __attribute__((ext_vector_type(4)));   // native vec for nt store

__device__ __forceinline__ int bucket(float pass) {
    // EXACT reference arithmetic: f32 div, f32 mul, trunc toward 0, clamp.
    float r = pass / 100000.0f * 100.0f;
    int v = (int)r;
    v = v < 0 ? 0 : v;
    v = v > NBINS ? NBINS : v;
    return v;
}

__global__ __launch_bounds__(256)
void fused_encode_kernel(const float* __restrict__ ts,
                         const float* __restrict__ W,
                         const float* __restrict__ bias,
                         vf4* __restrict__ out) {
    // Hot fused table rows 0..3: tbl[k*128+e] = W[e*101+k] + bias[e]  (2 KB).
    // i = e*4+k ordering: consecutive threads read consecutive W addresses.
    __shared__ float tbl[4 * EMB];
    for (int i = threadIdx.x; i < 4 * EMB; i += 256) {
        const int e = i >> 2;                 // 0..127
        const int k = i & 3;                  // 0..3
        tbl[k * EMB + e] = W[e * (NBINS + 1) + k] + bias[e];
    }
    __syncthreads();

    const int lane  = threadIdx.x & 31;       // float4 slot within a row
    const int group = threadIdx.x >> 5;       // 0..7, 4 rows each
    const int step  = gridDim.x * 32;
    const vf4* __restrict__ t4 = (const vf4*)tbl;

    for (int base = blockIdx.x * 32; base < NROWS; base += step) {
        const int r0 = base + group * 4;
        float4 t   = *(const float4*)&ts[r0];              // broadcast within group
        float prev = ts[r0 == 0 ? 0 : r0 - 1];             // broadcast
        // Row r0 is the only possible sequence start in this quad (LLEN%4==0).
        float p0 = (r0 & (LLEN - 1)) ? t.x - prev : 0.0f;
        const int q0 = bucket(p0);
        const int q1 = bucket(t.y - t.x);
        const int q2 = bucket(t.z - t.y);
        const int q3 = bucket(t.w - t.z);

        const size_t o = (size_t)r0 * (EMB / 4) + lane;
        if ((q0 | q1 | q2 | q3) < 4) {
            // Fast path (always, in practice). Group-uniform branch.
            vf4 v0 = t4[q0 * (EMB / 4) + lane];             // LDS, conflict-free
            vf4 v1 = t4[q1 * (EMB / 4) + lane];
            vf4 v2 = t4[q2 * (EMB / 4) + lane];
            vf4 v3 = t4[q3 * (EMB / 4) + lane];
            __builtin_nontemporal_store(v0, &out[o]);       // write-once: nt hint
            __builtin_nontemporal_store(v1, &out[o + 32]);
            __builtin_nontemporal_store(v2, &out[o + 64]);
            __builtin_nontemporal_store(v3, &out[o + 96]);
        } else {
            // Cold correctness path: gather straight from W (stride-101 rows).
            const float* bb = &bias[lane * 4];
            const int qs[4] = {q0, q1, q2, q3};
            #pragma unroll
            for (int j = 0; j < 4; ++j) {
                const int q = qs[j];
                vf4 v;
                v.x = W[(lane * 4 + 0) * (NBINS + 1) + q] + bb[0];
                v.y = W[(lane * 4 + 1) * (NBINS + 1) + q] + bb[1];
                v.z = W[(lane * 4 + 2) * (NBINS + 1) + q] + bb[2];
                v.w = W[(lane * 4 + 3) * (NBINS + 1) + q] + bb[3];
                __builtin_nontemporal_store(v, &out[o + j * 32]);
            }
        }
    }
}

extern "C" void kernel_launch(void* const* d_in, const int* in_sizes, int n_in,
                              void* d_out, int out_size, void* d_ws, size_t ws_size,
                              hipStream_t stream) {
    const float* ts   = (const float*)d_in[1];
    const float* W    = (const float*)d_in[2];
    const float* bias = (const float*)d_in[3];
    (void)d_ws; (void)ws_size;

    // 2048 blocks x 256 threads: 8 grid-stride iterations per thread,
    // 16 KB contiguous stores per block-iteration.
    fused_encode_kernel<<<2048, 256, 0, stream>>>(ts, W, bias, (vf4*)d_out);
}

// Round 6
// 47.170 us; speedup vs baseline: 1.1102x; 1.1102x over previous
//
#include <hip/hip_runtime.h>

// IntervalTimeEncoder: out[b,l,e] = W[e, idx(b,l)] + bias[e]
// idx(b,l) = clamp(trunc((ts[b,l]-ts[b,l-1]) / 100000.0f * 100.0f), 0, 100), idx(b,0)=0
//
// Inputs (setup_inputs order):
//   d_in[0] = inputs    int64  [128,4096]   (UNUSED by reference)
//   d_in[1] = timestamp f32    [128,4096]
//   d_in[2] = W         f32    [128,101]
//   d_in[3] = b         f32    [128]
// Output: f32 [128,4096,128] = 256 MiB -> write-streaming bound.
//
// Round 6: nt-stores REVERTED (r5: 52.4 us vs 46.4 — nt bypasses L2 write
// buffering on gfx950, hurts streaming stores). New: wave-contiguous stores.
// One 64-lane WAVE owns 8 consecutive rows; store j covers rows
// {base+2j, base+2j+1} = one contiguous 1 KB per store instruction (was
// 2 x 512 B segments 2 KB apart). Lanes<32 compute even-row buckets,
// lanes>=32 odd-row buckets. idx in {0..3} in practice (gaps <= 3000);
// cold W-direct path keeps correctness for any idx.

#define NBINS  100
#define EMB    128
#define LLEN   4096
#define NROWS  (128 * LLEN)            // 524288

typedef float vf4 __attribute__((ext_vector_type(4)));

__device__ __forceinline__ int bucket(float pass) {
    // EXACT reference arithmetic: f32 div, f32 mul, trunc toward 0, clamp.
    float r = pass / 100000.0f * 100.0f;
    int v = (int)r;
    v = v < 0 ? 0 : v;
    v = v > NBINS ? NBINS : v;
    return v;
}

__global__ __launch_bounds__(256)
void fused_encode_kernel(const float* __restrict__ ts,
                         const float* __restrict__ W,
                         const float* __restrict__ bias,
                         vf4* __restrict__ out) {
    // Hot fused table rows 0..3: tbl[k*128+e] = W[e*101+k] + bias[e]  (2 KB).
    __shared__ float tbl[4 * EMB];
    for (int i = threadIdx.x; i < 4 * EMB; i += 256) {
        const int e = i >> 2;                 // 0..127
        const int k = i & 3;                  // 0..3
        tbl[k * EMB + e] = W[e * (NBINS + 1) + k] + bias[e];
    }
    __syncthreads();

    const int lane = threadIdx.x & 63;        // lane within wave
    const int wid  = threadIdx.x >> 6;        // 0..3 waves/block
    const int sel  = lane >> 5;               // 0: even rows, 1: odd rows
    const int slot = lane & 31;               // float4 slot within a row
    const int step = gridDim.x * 32;          // rows per grid-iteration
    const vf4* __restrict__ t4 = (const vf4*)tbl;

    for (int base = blockIdx.x * 32 + wid * 8; base < NROWS; base += step) {
        // 8 consecutive rows per wave. base % 8 == 0 -> 32B-aligned ts loads.
        vf4 t0 = *(const vf4*)&ts[base];                   // rows base..base+3
        vf4 t1 = *(const vf4*)&ts[base + 4];               // rows base+4..base+7
        float prev = ts[base == 0 ? 0 : base - 1];         // broadcast

        // Diffs for this lane-half's 4 rows (rows base+2j+sel, j=0..3).
        float d0, d1, d2, d3;
        if (sel == 0) {
            d0 = (base & (LLEN - 1)) ? t0.x - prev : 0.0f; // row base (seq start?)
            d1 = t0.z - t0.y;                              // row base+2
            d2 = t1.x - t0.w;                              // row base+4
            d3 = t1.z - t1.y;                              // row base+6
        } else {
            d0 = t0.y - t0.x;                              // row base+1
            d1 = t0.w - t0.z;                              // row base+3
            d2 = t1.y - t1.x;                              // row base+5
            d3 = t1.w - t1.z;                              // row base+7
        }
        const int q0 = bucket(d0);
        const int q1 = bucket(d1);
        const int q2 = bucket(d2);
        const int q3 = bucket(d3);

        if (__builtin_amdgcn_ballot_w64((q0 | q1 | q2 | q3) >= 4) == 0ull) {
            // Fast path (always, in practice). Each store: rows base+2j and
            // base+2j+1 -> one contiguous 1 KB per 64-lane store instruction.
            vf4 v0 = t4[q0 * 32 + slot];                   // LDS, conflict-free
            vf4 v1 = t4[q1 * 32 + slot];
            vf4 v2 = t4[q2 * 32 + slot];
            vf4 v3 = t4[q3 * 32 + slot];
            const size_t o = (size_t)base * 32 + lane;     // row base+sel, slot
            out[o]       = v0;
            out[o + 64]  = v1;                             // +2 rows
            out[o + 128] = v2;
            out[o + 192] = v3;
        } else {
            // Cold correctness path: gather straight from W (stride-101 rows).
            const int qs[4] = {q0, q1, q2, q3};
            #pragma unroll
            for (int j = 0; j < 4; ++j) {
                const int q = qs[j];
                vf4 v;
                v.x = W[(slot * 4 + 0) * (NBINS + 1) + q] + bias[slot * 4 + 0];
                v.y = W[(slot * 4 + 1) * (NBINS + 1) + q] + bias[slot * 4 + 1];
                v.z = W[(slot * 4 + 2) * (NBINS + 1) + q] + bias[slot * 4 + 2];
                v.w = W[(slot * 4 + 3) * (NBINS + 1) + q] + bias[slot * 4 + 3];
                out[(size_t)base * 32 + lane + j * 64] = v;
            }
        }
    }
}

extern "C" void kernel_launch(void* const* d_in, const int* in_sizes, int n_in,
                              void* d_out, int out_size, void* d_ws, size_t ws_size,
                              hipStream_t stream) {
    const float* ts   = (const float*)d_in[1];
    const float* W    = (const float*)d_in[2];
    const float* bias = (const float*)d_in[3];
    (void)d_ws; (void)ws_size;

    // 2048 blocks x 256 threads (4 waves): 8 grid-stride iterations/wave,
    // 16 KB contiguous per block-iteration, full 32-waves/CU occupancy.
    fused_encode_kernel<<<2048, 256, 0, stream>>>(ts, W, bias, (vf4*)d_out);
}

// Round 7
// 46.133 us; speedup vs baseline: 1.1352x; 1.0225x over previous
//
#include <hip/hip_runtime.h>

// IntervalTimeEncoder: out[b,l,e] = W[e, idx(b,l)] + bias[e]
// idx(b,l) = clamp(trunc((ts[b,l]-ts[b,l-1]) / 100000.0f * 100.0f), 0, 100), idx(b,0)=0
//
// Inputs (setup_inputs order):
//   d_in[0] = inputs    int64  [128,4096]   (UNUSED by reference)
//   d_in[1] = timestamp f32    [128,4096]
//   d_in[2] = W         f32    [128,101]
//   d_in[3] = b         f32    [128]
// Output: f32 [128,4096,128] = 256 MiB -> write-streaming bound.
//
// FINAL (round-3 structure, best measured: 46.4 us ~ 92% of the 7.05 TB/s
// fill-rate write ceiling; residual is fixed launch/ramp overhead).
// Probe history: split prep+gather 49.7 | this 46.4 | +nt stores 52.4
// (nt bypasses L2 write buffering on gfx950 — reverted) | wave-contiguous
// 1KB stores 47.2 (neutral; L2 coalesces 2x512B equally well).
//
// Structure: single kernel. Data property: gaps <= 3000 => idx in {0,1,2,3}
// always (idx 0 at row starts; f32 cumsum rounding can nudge a diff just
// past 3000 -> 3). Each block builds the 4 hot fused table rows
// (tbl[k][e] = W[e][k]+b[e], 2 KB) in LDS, then streams: float4 ts load ->
// 4 independent div/trunc/clamp -> 4 ds_read_b128 -> 4 independent float4
// stores (16 KB contiguous per block-iteration). Cold (never-taken)
// W-direct path keeps correctness for idx > 3.

#define NBINS  100
#define EMB    128
#define LLEN   4096
#define NROWS  (128 * LLEN)            // 524288

__device__ __forceinline__ int bucket(float pass) {
    // EXACT reference arithmetic: f32 div, f32 mul, trunc toward 0, clamp.
    float r = pass / 100000.0f * 100.0f;
    int v = (int)r;
    v = v < 0 ? 0 : v;
    v = v > NBINS ? NBINS : v;
    return v;
}

__global__ __launch_bounds__(256)
void fused_encode_kernel(const float* __restrict__ ts,
                         const float* __restrict__ W,
                         const float* __restrict__ bias,
                         float4* __restrict__ out) {
    // Hot fused table rows 0..3: tbl[k*128+e] = W[e*101+k] + bias[e]  (2 KB).
    // i = e*4+k ordering: consecutive threads read consecutive W addresses.
    __shared__ float tbl[4 * EMB];
    for (int i = threadIdx.x; i < 4 * EMB; i += 256) {
        const int e = i >> 2;                 // 0..127
        const int k = i & 3;                  // 0..3
        tbl[k * EMB + e] = W[e * (NBINS + 1) + k] + bias[e];
    }
    __syncthreads();

    const int lane  = threadIdx.x & 31;       // float4 slot within a row
    const int group = threadIdx.x >> 5;       // 0..7, 4 rows each
    const int step  = gridDim.x * 32;
    const float4* __restrict__ t4 = (const float4*)tbl;

    for (int base = blockIdx.x * 32; base < NROWS; base += step) {
        const int r0 = base + group * 4;
        float4 t   = *(const float4*)&ts[r0];              // broadcast within group
        float prev = ts[r0 == 0 ? 0 : r0 - 1];             // broadcast
        // Row r0 is the only possible sequence start in this quad (LLEN%4==0).
        float p0 = (r0 & (LLEN - 1)) ? t.x - prev : 0.0f;
        const int q0 = bucket(p0);
        const int q1 = bucket(t.y - t.x);
        const int q2 = bucket(t.z - t.y);
        const int q3 = bucket(t.w - t.z);

        const size_t o = (size_t)r0 * (EMB / 4) + lane;
        if ((q0 | q1 | q2 | q3) < 4) {
            // Fast path (always, in practice). Group-uniform branch.
            float4 v0 = t4[q0 * (EMB / 4) + lane];          // LDS, conflict-free
            float4 v1 = t4[q1 * (EMB / 4) + lane];
            float4 v2 = t4[q2 * (EMB / 4) + lane];
            float4 v3 = t4[q3 * (EMB / 4) + lane];
            out[o]      = v0;                               // 4 independent streams
            out[o + 32] = v1;
            out[o + 64] = v2;
            out[o + 96] = v3;
        } else {
            // Cold correctness path: gather straight from W (stride-101 rows).
            float4 bb = *(const float4*)&bias[lane * 4];
            const int qs[4] = {q0, q1, q2, q3};
            #pragma unroll
            for (int j = 0; j < 4; ++j) {
                const int q = qs[j];
                float4 v;
                v.x = W[(lane * 4 + 0) * (NBINS + 1) + q] + bb.x;
                v.y = W[(lane * 4 + 1) * (NBINS + 1) + q] + bb.y;
                v.z = W[(lane * 4 + 2) * (NBINS + 1) + q] + bb.z;
                v.w = W[(lane * 4 + 3) * (NBINS + 1) + q] + bb.w;
                out[o + j * 32] = v;
            }
        }
    }
}

extern "C" void kernel_launch(void* const* d_in, const int* in_sizes, int n_in,
                              void* d_out, int out_size, void* d_ws, size_t ws_size,
                              hipStream_t stream) {
    const float* ts   = (const float*)d_in[1];
    const float* W    = (const float*)d_in[2];
    const float* bias = (const float*)d_in[3];
    (void)d_ws; (void)ws_size;

    // 2048 blocks x 256 threads: 8 grid-stride iterations per thread,
    // 16 KB contiguous stores per block-iteration.
    fused_encode_kernel<<<2048, 256, 0, stream>>>(ts, W, bias, (float4*)d_out);
}